// Round 9
// baseline (213.214 us; speedup 1.0000x reference)
//
#include <hip/hip_runtime.h>
#include <hip/hip_bf16.h>
#include <cstdint>

// B=2, S=2048, E=1024, H=16, HD=64
#define SS 2048
#define EE 1024
#define HH 16
#define HDD 64

typedef __attribute__((ext_vector_type(8))) __bf16 bf16x8;
typedef __attribute__((ext_vector_type(4))) float f32x4;

#define MFMA16(a, b, c) __builtin_amdgcn_mfma_f32_16x16x32_bf16((a), (b), (c), 0, 0, 0)

__device__ __forceinline__ unsigned short f2bf(float f) {
    unsigned int u = __builtin_bit_cast(unsigned int, f);
    u += 0x7FFFu + ((u >> 16) & 1u);   // round-to-nearest-even
    return (unsigned short)(u >> 16);
}

// async global->LDS, 16B per lane; LDS dest is wave-uniform base + lane*16
__device__ __forceinline__ void gll16(const unsigned short* g, unsigned short* l) {
    __builtin_amdgcn_global_load_lds(
        (__attribute__((address_space(1))) unsigned int*)g,
        (__attribute__((address_space(3))) unsigned int*)l, 16, 0, 0);
}

// v_permlane32_swap_b32: a' = {A.low32, B.low32}, b' = {A.high32, B.high32}
__device__ __forceinline__ void pl32swap(unsigned int& a, unsigned int& b) {
#if __has_builtin(__builtin_amdgcn_permlane32_swap)
    auto r = __builtin_amdgcn_permlane32_swap(a, b, false, false);
    a = r[0]; b = r[1];
#else
    unsigned int as = __shfl_xor(a, 32, 64), bs = __shfl_xor(b, 32, 64);
    const bool hi = (threadIdx.x & 32) != 0;
    unsigned int na = hi ? bs : a, nb = hi ? b : as;
    a = na; b = nb;
#endif
}

// v_permlane16_swap_b32: a' = {A.r0, B.r0, A.r2, B.r2}, b' = {A.r1, B.r1, A.r3, B.r3}  (16-lane rows)
__device__ __forceinline__ void pl16swap(unsigned int& a, unsigned int& b) {
#if __has_builtin(__builtin_amdgcn_permlane16_swap)
    auto r = __builtin_amdgcn_permlane16_swap(a, b, false, false);
    a = r[0]; b = r[1];
#else
    unsigned int as = __shfl_xor(a, 16, 64), bs = __shfl_xor(b, 16, 64);
    const bool odd = (threadIdx.x & 16) != 0;
    unsigned int na = odd ? bs : a, nb = odd ? b : as;
    a = na; b = nb;
#endif
}

// ---------------- fp32 -> bf16 convert (x + 4 weights) ----------------
__global__ __launch_bounds__(256) void cvt_all(
    const float* __restrict__ x, const float* __restrict__ wq, const float* __restrict__ wk,
    const float* __restrict__ wv, const float* __restrict__ wo,
    unsigned short* __restrict__ xb, unsigned short* __restrict__ wqb, unsigned short* __restrict__ wkb,
    unsigned short* __restrict__ wvb, unsigned short* __restrict__ wob) {
    int idx = blockIdx.x * 256 + threadIdx.x;
    int i4 = idx << 2;                       // 4 floats per thread
    const float* src;
    unsigned short* dst;
    int off;
    if (i4 < 4194304) { src = x; dst = xb; off = i4; }
    else {
        int w = (i4 - 4194304) >> 20;        // 0..3
        off = (i4 - 4194304) & 1048575;
        if (w == 0) { src = wq; dst = wqb; }
        else if (w == 1) { src = wk; dst = wkb; }
        else if (w == 2) { src = wv; dst = wvb; }
        else { src = wo; dst = wob; }
    }
    float4 v = *(const float4*)&src[off];
    unsigned int p0 = (unsigned int)f2bf(v.x) | ((unsigned int)f2bf(v.y) << 16);
    unsigned int p1 = (unsigned int)f2bf(v.z) | ((unsigned int)f2bf(v.w) << 16);
    uint2 u; u.x = p0; u.y = p1;
    *(uint2*)&dst[off] = u;
}

// ---------------- BT GEMM, A in LDS (double-buffered), B REG-STREAMED ----------------
// ROUND-19: gemm_qkv was LDS-pipe-saturated (per block-iter: 32KB ds_read + 16KB
// staging = 48KB vs ~47KB/slot of LDS BW at 3 blocks/CU -> MfmaUtil 19%). B is a
// 2MB L2-resident weight matrix; its fragments are loaded DIRECTLY from global
// into registers, prefetched one iteration ahead (issued post-barrier, consumed
// next iter; the __syncthreads vmcnt(0) drain guarantees arrival). LDS traffic
// halves (48->24 KB/block-iter), LDS alloc 32->16 KB. A path unchanged.
// Logical k-chunk of the old swizzled LDS-B read == quad -> global offset
// (bn+wn+j*16+l15)*1024 + it*32 + quad*8 (no swizzle in global).
// MODE 0: bf16 out per-head [B,H,S,HD]  (Q)
// MODE 1: fp32 out [M,N]                (final projection)
// MODE 3: bf16 K in MFMA A-fragment order
// MODE 4: bf16 V in MFMA B-fragment order
template <int MODE, int BMT, int BNT>
__device__ __forceinline__ void gemm_core(
    unsigned short* __restrict__ lsA,        // [2][BMT*32]
    const unsigned short* __restrict__ A, const unsigned short* __restrict__ W,
    const float* __restrict__ bias, void* __restrict__ out, int bm, int bn) {
    constexpr int IT = BMT / 32, JT = BNT / 32;
    constexpr int ASTR = BMT * 32;
    const int t = threadIdx.x;
    const int lane = t & 63, l15 = lane & 15, quad = lane >> 4;
    const int wave = t >> 6;
    const int wm = (wave >> 1) * (BMT / 2), wn = (wave & 1) * (BNT / 2);

    // A staging: lane t -> physical chunk (t&3) of row (t>>2); load logical chunk (t&3)^((t>>3)&3)
    const int cg = ((t & 3) ^ ((t >> 3) & 3)) * 8;
    const unsigned short* ga = A + (size_t)(bm + (t >> 2)) * 1024 + cg;

    // B fragments straight from global (L2-resident weights), fragment order
    const unsigned short* gw = W + (size_t)(bn + wn + l15) * 1024 + quad * 8;

    f32x4 acc[IT][JT];
    for (int i = 0; i < IT; i++)
        for (int j = 0; j < JT; j++) acc[i][j] = (f32x4){0.f, 0.f, 0.f, 0.f};

    const int swz = (l15 >> 1) & 3;  // (row>>1)&3 for row = wX + i*16 + l15

    // prefetch B fragments for it=0
    bf16x8 bnx[JT];
    for (int j = 0; j < JT; j++)
        bnx[j] = *(const bf16x8*)&gw[(size_t)j * 16384];

    // stage A K-slab 0 into buffer 0
    gll16(ga, &lsA[t * 8]);
    if (BMT == 128) gll16(ga + 64 * 1024, &lsA[2048 + t * 8]);

    for (int it = 0; it < 32; it++) {
        const int cur = it & 1, nxt = cur ^ 1;
        __syncthreads();  // cur A-staging + B-prefetch drained (vmcnt(0) before barrier)

        bf16x8 bcur[JT];
        for (int j = 0; j < JT; j++) bcur[j] = bnx[j];

        if (it < 31) {
            const int k0 = (it + 1) * 32;
            gll16(ga + k0, &lsA[nxt * ASTR + t * 8]);
            if (BMT == 128) gll16(ga + k0 + 64 * 1024, &lsA[nxt * ASTR + 2048 + t * 8]);
            for (int j = 0; j < JT; j++)
                bnx[j] = *(const bf16x8*)&gw[(size_t)j * 16384 + k0];   // lands by next barrier
        }

        bf16x8 af[IT];
        for (int i = 0; i < IT; i++)
            af[i] = *(const bf16x8*)&lsA[cur * ASTR + (wm + i * 16 + l15) * 32 + ((quad ^ swz) * 8)];
        for (int i = 0; i < IT; i++)
            for (int j = 0; j < JT; j++) acc[i][j] = MFMA16(af[i], bcur[j], acc[i][j]);
    }

    // epilogue: C row = quad*4+reg, col = l15 per 16x16 tile (m89-verified)
    for (int j = 0; j < JT; j++) {
        int n = bn + wn + j * 16 + l15;
        float bj = bias[n];
        for (int i = 0; i < IT; i++) {
            int m0 = bm + wm + i * 16 + quad * 4;
            int srow0 = m0 & 2047, bidx = m0 >> 11;
            if (MODE == 3) {
                size_t headb = ((size_t)bidx * HH + (n >> 6)) * (SS * HDD);
                size_t base = headb + (size_t)(srow0 >> 6) * 4096 +
                              (size_t)(((srow0 >> 4) & 3) * 8 + ((n & 63) >> 3)) * 128 + (n & 7);
                for (int rg = 0; rg < 4; rg++)
                    ((unsigned short*)out)[base + (size_t)((srow0 & 15) + rg) * 8] = f2bf(acc[i][j][rg] + bj);
            } else if (MODE == 4) {
                size_t headb = ((size_t)bidx * HH + (n >> 6)) * (SS * HDD);
                size_t addr = headb + (size_t)(srow0 >> 6) * 4096 + (size_t)((n & 63) >> 4) * 1024 +
                              (size_t)(((srow0 >> 5) & 1) * 4 + ((srow0 >> 3) & 3)) * 128 +
                              (size_t)(n & 15) * 8 + (srow0 & 7);
                float v0 = acc[i][j][0] + bj, v1 = acc[i][j][1] + bj;
                float v2 = acc[i][j][2] + bj, v3 = acc[i][j][3] + bj;
                uint2 w;
                w.x = (unsigned int)f2bf(v0) | ((unsigned int)f2bf(v1) << 16);
                w.y = (unsigned int)f2bf(v2) | ((unsigned int)f2bf(v3) << 16);
                *(uint2*)&((unsigned short*)out)[addr] = w;
            } else {
                for (int rg = 0; rg < 4; rg++) {
                    float val = acc[i][j][rg] + bj;
                    int m = m0 + rg;
                    if (MODE == 0) {
                        ((unsigned short*)out)[(((size_t)(m >> 11) * HH + (n >> 6)) * SS + (m & 2047)) * HDD + (n & 63)] = f2bf(val);
                    } else {
                        ((float*)out)[(size_t)m * 1024 + n] = val;
                    }
                }
            }
        }
    }
}

// grid 768 1-D; XCD swizzle: same-by blocks share an XCD
__global__ __launch_bounds__(256) void gemm_qkv(
    const unsigned short* __restrict__ xb,
    const unsigned short* __restrict__ wqb, const unsigned short* __restrict__ wkb,
    const unsigned short* __restrict__ wvb,
    const float* __restrict__ bq, const float* __restrict__ bk, const float* __restrict__ bv,
    unsigned short* qb, unsigned short* kb, unsigned short* vtb) {
    __shared__ unsigned short shA[2 * 4096];   // 16 KB, shared across all 3 instantiations
    const int blk = blockIdx.x;
    const int u = blk & 7, r = blk >> 3;
    const int by = u + 8 * (r & 3);          // 0..31
    const int rest = r >> 2;                 // 0..23
    const int bx = rest & 7, z = rest >> 3;  // 0..7, 0..2
    if (z == 0)      gemm_core<0, 128, 128>(shA, xb, wqb, bq, qb,  by * 128, bx * 128);
    else if (z == 1) gemm_core<3, 128, 128>(shA, xb, wkb, bk, kb,  by * 128, bx * 128);
    else             gemm_core<4, 128, 128>(shA, xb, wvb, bv, vtb, by * 128, bx * 128);
}

// grid 256 1-D (128x128 tiles)
__global__ __launch_bounds__(256) void gemm_out(
    const unsigned short* __restrict__ ob, const unsigned short* __restrict__ wob,
    const float* __restrict__ bo, float* __restrict__ out) {
    __shared__ unsigned short shA[2 * 4096];
    const int blk = blockIdx.x;
    const int u = blk & 7, r = blk >> 3;     // r: 0..31
    const int by = u + 8 * (r & 3);          // 0..31
    const int bx = r >> 2;                   // 0..7
    gemm_core<1, 128, 128>(shA, ob, wob, bo, out, by * 128, bx * 128);
}

// ---------------- flash attention: INTRA-BLOCK SPLIT-K, 8 waves ----------------
// ROUND-16 state kept: 1-deep pipeline (PV(kt-1) register-only after barrier),
// setprio around pv(), K/V dbuf, 1 barrier/iter, in-register P transpose.
__global__ __launch_bounds__(512, 4) void attn_fwd(
    const unsigned short* __restrict__ qb, const unsigned short* __restrict__ kb,
    const unsigned short* __restrict__ vtb, unsigned short* __restrict__ ob) {
    __shared__ unsigned short sh[32768];  // lsK[2][2][4096] | lsV[2][2][4096]; combine aliases fit
    unsigned short* lsK = sh;
    unsigned short* lsV = sh + 16384;
    const int t = threadIdx.x, lane = t & 63, l15 = lane & 15, quad = lane >> 4;
    const int wave = t >> 6;          // 0..7
    const int half = wave >> 2;       // key-half
    const int wq = wave & 3;          // q-wave within half
    const int tg = t & 255;           // thread index within half-group
    const int blk = blockIdx.x;
    const int u = blk & 7, r = blk >> 3;
    const int bh = u + 8 * (r & 3);   // 0..31: 4 heads per XCD
    const int qt = r >> 2;            // 0..15
    const size_t hoff = (size_t)bh * (SS * HDD);
    const float C = 0.125f * 1.44269504088896f;  // 1/sqrt(HD) * log2(e)

    bf16x8 qf[2][2];
    const int qrow = qt * 128 + wq * 32;
    for (int i = 0; i < 2; i++)
        for (int ks = 0; ks < 2; ks++) {
            bf16x8 raw = *(const bf16x8*)&qb[hoff + (size_t)(qrow + i * 16 + l15) * HDD + ks * 32 + quad * 8];
            unsigned short tmp[8];
            *(bf16x8*)tmp = raw;
            for (int j = 0; j < 8; j++) {
                float f = __builtin_bit_cast(float, (unsigned int)tmp[j] << 16);
                tmp[j] = f2bf(f * C);
            }
            qf[i][ks] = *(const bf16x8*)tmp;
        }

    unsigned short onesbuf[8];
    for (int j = 0; j < 8; j++) onesbuf[j] = 0x3F80;  // bf16 1.0
    const bf16x8 onesf = *(const bf16x8*)onesbuf;

    f32x4 lacc[2];
    f32x4 o[2][4];
    for (int i = 0; i < 2; i++) {
        lacc[i] = (f32x4){0.f, 0.f, 0.f, 0.f};
        for (int jh = 0; jh < 4; jh++) o[i][jh] = (f32x4){0.f, 0.f, 0.f, 0.f};
    }

    const unsigned short* gk = kb + hoff + (size_t)half * 16 * 4096;
    const unsigned short* gv = vtb + hoff + (size_t)half * 16 * 4096;
    const int foff = quad * 128 + l15 * 8;

    auto stage = [&](int buf, int tile) {
        unsigned short* dk = lsK + buf * 8192 + half * 4096;
        unsigned short* dv = lsV + buf * 8192 + half * 4096;
        const unsigned short* sk = gk + tile * 4096;
        const unsigned short* sv = gv + tile * 4096;
        gll16(sk + tg * 8, dk + tg * 8);
        gll16(sk + 2048 + tg * 8, dk + 2048 + tg * 8);
        gll16(sv + tg * 8, dv + tg * 8);
        gll16(sv + 2048 + tg * 8, dv + 2048 + tg * 8);
    };

    bf16x8 pfp[2][2];
    bf16x8 vfp[4][2];

    auto qk_pack = [&](const unsigned short* myK) {
        bf16x8 kfr[4][2];
        for (int j = 0; j < 4; j++)
            for (int ks = 0; ks < 2; ks++)
                kfr[j][ks] = *(const bf16x8*)&myK[j * 1024 + ks * 512 + foff];
        f32x4 st[2][4];
        for (int j = 0; j < 4; j++)
            for (int i = 0; i < 2; i++) {
                f32x4 z = (f32x4){0.f, 0.f, 0.f, 0.f};
                z = MFMA16(kfr[j][0], qf[i][0], z);
                z = MFMA16(kfr[j][1], qf[i][1], z);
                st[i][j] = z;
            }
        for (int i = 0; i < 2; i++) {
            unsigned int W[4][2];
            for (int j = 0; j < 4; j++) {
                float e0 = __builtin_amdgcn_exp2f(st[i][j][0]);
                float e1 = __builtin_amdgcn_exp2f(st[i][j][1]);
                float e2 = __builtin_amdgcn_exp2f(st[i][j][2]);
                float e3 = __builtin_amdgcn_exp2f(st[i][j][3]);
                W[j][0] = (__builtin_bit_cast(unsigned int, e0) >> 16) |
                          (__builtin_bit_cast(unsigned int, e1) & 0xFFFF0000u);
                W[j][1] = (__builtin_bit_cast(unsigned int, e2) >> 16) |
                          (__builtin_bit_cast(unsigned int, e3) & 0xFFFF0000u);
            }
            unsigned int P0[4], P1[4];
            for (int h = 0; h < 2; h++) {
                unsigned int x = W[0][h], y = W[1][h];
                pl32swap(x, y);
                pl16swap(x, y);
                P0[h] = x; P0[2 + h] = y;
                unsigned int x2 = W[2][h], y2 = W[3][h];
                pl32swap(x2, y2);
                pl16swap(x2, y2);
                P1[h] = x2; P1[2 + h] = y2;
            }
            union { unsigned int u4[4]; bf16x8 v; } cv0, cv1;
            for (int p = 0; p < 4; p++) { cv0.u4[p] = P0[p]; cv1.u4[p] = P1[p]; }
            pfp[i][0] = cv0.v;
            pfp[i][1] = cv1.v;
        }
    };
    auto readV = [&](const unsigned short* myV) {
        for (int jh = 0; jh < 4; jh++) {
            vfp[jh][0] = *(const bf16x8*)&myV[jh * 1024 + foff];
            vfp[jh][1] = *(const bf16x8*)&myV[jh * 1024 + 512 + foff];
        }
    };
    auto pv = [&]() {
        __builtin_amdgcn_s_setprio(1);
        for (int jh = 0; jh < 4; jh++)
            for (int i = 0; i < 2; i++) {
                o[i][jh] = MFMA16(pfp[i][0], vfp[jh][0], o[i][jh]);
                o[i][jh] = MFMA16(pfp[i][1], vfp[jh][1], o[i][jh]);
            }
        for (int i = 0; i < 2; i++) {
            lacc[i] = MFMA16(pfp[i][0], onesf, lacc[i]);
            lacc[i] = MFMA16(pfp[i][1], onesf, lacc[i]);
        }
        __builtin_amdgcn_s_setprio(0);
    };

    stage(0, 0);

    __syncthreads();
    stage(1, 1);
    qk_pack(lsK + half * 4096);
    readV(lsV + half * 4096);

    for (int kt = 1; kt < 16; kt++) {
        const int cur = kt & 1;
        __syncthreads();
        if (kt < 15) stage(cur ^ 1, kt + 1);
        pv();
        const unsigned short* myK = lsK + cur * 8192 + half * 4096;
        const unsigned short* myV = lsV + cur * 8192 + half * 4096;
        qk_pack(myK);
        readV(myV);
    }
    pv();

    __syncthreads();
    float* cb = (float*)sh;
    float* lb = cb + 8192;
    const int lslot = wq * 64 + lane;
    if (half == 1) {
        for (int i = 0; i < 2; i++)
            for (int jh = 0; jh < 4; jh++)
                for (int rg = 0; rg < 4; rg++)
                    cb[(i * 16 + jh * 4 + rg) * 256 + lslot] = o[i][jh][rg];
        for (int i = 0; i < 2; i++)
            for (int rg = 0; rg < 4; rg++)
                lb[(i * 4 + rg) * 256 + lslot] = lacc[i][rg];
    }
    __syncthreads();
    if (half == 0) {
        const int b = bh >> 4, h = bh & 15;
        for (int i = 0; i < 2; i++)
            for (int rg = 0; rg < 4; rg++) {
                float inv = 1.f / (lacc[i][rg] + lb[(i * 4 + rg) * 256 + lslot]);
                int srow = qrow + i * 16 + quad * 4 + rg;
                size_t rowoff = ((size_t)b * SS + srow) * EE + h * 64;
                for (int jh = 0; jh < 4; jh++) {
                    float val = o[i][jh][rg] + cb[(i * 16 + jh * 4 + rg) * 256 + lslot];
                    ob[rowoff + jh * 16 + l15] = f2bf(val * inv);
                }
            }
    }
}

extern "C" void kernel_launch(void* const* d_in, const int* in_sizes, int n_in,
                              void* d_out, int out_size, void* d_ws, size_t ws_size,
                              hipStream_t stream) {
    const float* x  = (const float*)d_in[0];
    const float* wq = (const float*)d_in[1];
    const float* bq = (const float*)d_in[2];
    const float* wk = (const float*)d_in[3];
    const float* bk = (const float*)d_in[4];
    const float* wv = (const float*)d_in[5];
    const float* bv = (const float*)d_in[6];
    const float* wo = (const float*)d_in[7];
    const float* bo = (const float*)d_in[8];

    char* ws = (char*)d_ws;
    unsigned short* xb  = (unsigned short*)(ws + 0);          // 8 MB, reused as ob after qkv
    unsigned short* wqb = (unsigned short*)(ws + 8388608);    // 2 MB
    unsigned short* wkb = (unsigned short*)(ws + 10485760);
    unsigned short* wvb = (unsigned short*)(ws + 12582912);
    unsigned short* wob = (unsigned short*)(ws + 14680064);
    unsigned short* qb  = (unsigned short*)(ws + 16777216);   // 8 MB each
    unsigned short* kb  = (unsigned short*)(ws + 25165824);   // K in fragment order
    unsigned short* vtb = (unsigned short*)(ws + 33554432);   // V in fragment order
    unsigned short* ob  = xb;  // x no longer needed after qkv GEMM

    cvt_all<<<8192, 256, 0, stream>>>(x, wq, wk, wv, wo, xb, wqb, wkb, wvb, wob);
    gemm_qkv<<<768, 256, 0, stream>>>(xb, wqb, wkb, wvb, bq, bk, bv, qb, kb, vtb);
    attn_fwd<<<512, 512, 0, stream>>>(qb, kb, vtb, ob);
    gemm_out<<<256, 256, 0, stream>>>(ob, wob, bo, (float*)d_out);
}

// Round 10
// 194.342 us; speedup vs baseline: 1.0971x; 1.0971x over previous
//
#include <hip/hip_runtime.h>
#include <hip/hip_bf16.h>
#include <cstdint>

// B=2, S=2048, E=1024, H=16, HD=64
#define SS 2048
#define EE 1024
#define HH 16
#define HDD 64

typedef __attribute__((ext_vector_type(8))) __bf16 bf16x8;
typedef __attribute__((ext_vector_type(4))) float f32x4;

#define MFMA16(a, b, c) __builtin_amdgcn_mfma_f32_16x16x32_bf16((a), (b), (c), 0, 0, 0)

__device__ __forceinline__ unsigned short f2bf(float f) {
    unsigned int u = __builtin_bit_cast(unsigned int, f);
    u += 0x7FFFu + ((u >> 16) & 1u);   // round-to-nearest-even
    return (unsigned short)(u >> 16);
}

// async global->LDS, 16B per lane; LDS dest is wave-uniform base + lane*16
__device__ __forceinline__ void gll16(const unsigned short* g, unsigned short* l) {
    __builtin_amdgcn_global_load_lds(
        (__attribute__((address_space(1))) unsigned int*)g,
        (__attribute__((address_space(3))) unsigned int*)l, 16, 0, 0);
}

// v_permlane32_swap_b32: a' = {A.low32, B.low32}, b' = {A.high32, B.high32}
__device__ __forceinline__ void pl32swap(unsigned int& a, unsigned int& b) {
#if __has_builtin(__builtin_amdgcn_permlane32_swap)
    auto r = __builtin_amdgcn_permlane32_swap(a, b, false, false);
    a = r[0]; b = r[1];
#else
    unsigned int as = __shfl_xor(a, 32, 64), bs = __shfl_xor(b, 32, 64);
    const bool hi = (threadIdx.x & 32) != 0;
    unsigned int na = hi ? bs : a, nb = hi ? b : as;
    a = na; b = nb;
#endif
}

// v_permlane16_swap_b32: a' = {A.r0, B.r0, A.r2, B.r2}, b' = {A.r1, B.r1, A.r3, B.r3}  (16-lane rows)
__device__ __forceinline__ void pl16swap(unsigned int& a, unsigned int& b) {
#if __has_builtin(__builtin_amdgcn_permlane16_swap)
    auto r = __builtin_amdgcn_permlane16_swap(a, b, false, false);
    a = r[0]; b = r[1];
#else
    unsigned int as = __shfl_xor(a, 16, 64), bs = __shfl_xor(b, 16, 64);
    const bool odd = (threadIdx.x & 16) != 0;
    unsigned int na = odd ? bs : a, nb = odd ? b : as;
    a = na; b = nb;
#endif
}

// ---------------- fp32 -> bf16 convert (x + 4 weights) ----------------
__global__ __launch_bounds__(256) void cvt_all(
    const float* __restrict__ x, const float* __restrict__ wq, const float* __restrict__ wk,
    const float* __restrict__ wv, const float* __restrict__ wo,
    unsigned short* __restrict__ xb, unsigned short* __restrict__ wqb, unsigned short* __restrict__ wkb,
    unsigned short* __restrict__ wvb, unsigned short* __restrict__ wob) {
    int idx = blockIdx.x * 256 + threadIdx.x;
    int i4 = idx << 2;                       // 4 floats per thread
    const float* src;
    unsigned short* dst;
    int off;
    if (i4 < 4194304) { src = x; dst = xb; off = i4; }
    else {
        int w = (i4 - 4194304) >> 20;        // 0..3
        off = (i4 - 4194304) & 1048575;
        if (w == 0) { src = wq; dst = wqb; }
        else if (w == 1) { src = wk; dst = wkb; }
        else if (w == 2) { src = wv; dst = wvb; }
        else { src = wo; dst = wob; }
    }
    float4 v = *(const float4*)&src[off];
    unsigned int p0 = (unsigned int)f2bf(v.x) | ((unsigned int)f2bf(v.y) << 16);
    unsigned int p1 = (unsigned int)f2bf(v.z) | ((unsigned int)f2bf(v.w) << 16);
    uint2 u; u.x = p0; u.y = p1;
    *(uint2*)&dst[off] = u;
}

// ---------------- BT GEMM, DOUBLE-BUFFERED (one barrier per K-iter) ----------------
// ROUND-20: FINAL CONFIG. Both operands LDS-staged (round-9's B reg-stream shifted
// 16KB/block-iter from LDS to L2 and exceeded the ~56 B/cy/CU L2 ceiling: 65us;
// staging deduplicates B across the 4 waves). 128x128 tiles (256^2 asm-pipeline
// port spilled acc: round-7). MODE 0: bf16 Q [B,H,S,HD]; MODE 1: fp32 [M,N];
// MODE 3: K in MFMA A-frag order; MODE 4: V in MFMA B-frag order.
template <int MODE, int BMT, int BNT>
__device__ __forceinline__ void gemm_core(
    unsigned short* __restrict__ lsA,        // [2][BMT*32]
    unsigned short* __restrict__ lsB,        // [2][BNT*32]
    const unsigned short* __restrict__ A, const unsigned short* __restrict__ W,
    const float* __restrict__ bias, void* __restrict__ out, int bm, int bn) {
    constexpr int IT = BMT / 32, JT = BNT / 32;
    constexpr int ASTR = BMT * 32, BSTR = BNT * 32;
    const int t = threadIdx.x;
    const int lane = t & 63, l15 = lane & 15, quad = lane >> 4;
    const int wave = t >> 6;
    const int wm = (wave >> 1) * (BMT / 2), wn = (wave & 1) * (BNT / 2);

    // staging: lane t -> physical chunk (t&3) of row (t>>2); load logical chunk (t&3)^((t>>3)&3)
    const int cg = ((t & 3) ^ ((t >> 3) & 3)) * 8;
    const unsigned short* ga = A + (size_t)(bm + (t >> 2)) * 1024 + cg;
    const unsigned short* gb = W + (size_t)(bn + (t >> 2)) * 1024 + cg;

    f32x4 acc[IT][JT];
    for (int i = 0; i < IT; i++)
        for (int j = 0; j < JT; j++) acc[i][j] = (f32x4){0.f, 0.f, 0.f, 0.f};

    const int swz = (l15 >> 1) & 3;  // (row>>1)&3 for row = wX + i*16 + l15

    // stage K-slab 0 into buffer 0
    gll16(ga, &lsA[t * 8]);
    if (BMT == 128) gll16(ga + 64 * 1024, &lsA[2048 + t * 8]);
    gll16(gb, &lsB[t * 8]);
    if (BNT == 128) gll16(gb + 64 * 1024, &lsB[2048 + t * 8]);

    for (int it = 0; it < 32; it++) {
        const int cur = it & 1, nxt = cur ^ 1;
        __syncthreads();  // cur staging done (issued a full body ago); prev reads of nxt drained

        if (it < 31) {
            const int k0 = (it + 1) * 32;
            gll16(ga + k0, &lsA[nxt * ASTR + t * 8]);
            if (BMT == 128) gll16(ga + k0 + 64 * 1024, &lsA[nxt * ASTR + 2048 + t * 8]);
            gll16(gb + k0, &lsB[nxt * BSTR + t * 8]);
            if (BNT == 128) gll16(gb + k0 + 64 * 1024, &lsB[nxt * BSTR + 2048 + t * 8]);
        }

        bf16x8 af[IT], bfr[JT];
        for (int i = 0; i < IT; i++)
            af[i] = *(const bf16x8*)&lsA[cur * ASTR + (wm + i * 16 + l15) * 32 + ((quad ^ swz) * 8)];
        for (int j = 0; j < JT; j++)
            bfr[j] = *(const bf16x8*)&lsB[cur * BSTR + (wn + j * 16 + l15) * 32 + ((quad ^ swz) * 8)];
        for (int i = 0; i < IT; i++)
            for (int j = 0; j < JT; j++) acc[i][j] = MFMA16(af[i], bfr[j], acc[i][j]);
    }

    // epilogue: C row = quad*4+reg, col = l15 per 16x16 tile (m89-verified)
    for (int j = 0; j < JT; j++) {
        int n = bn + wn + j * 16 + l15;
        float bj = bias[n];
        for (int i = 0; i < IT; i++) {
            int m0 = bm + wm + i * 16 + quad * 4;
            int srow0 = m0 & 2047, bidx = m0 >> 11;
            if (MODE == 3) {
                size_t headb = ((size_t)bidx * HH + (n >> 6)) * (SS * HDD);
                size_t base = headb + (size_t)(srow0 >> 6) * 4096 +
                              (size_t)(((srow0 >> 4) & 3) * 8 + ((n & 63) >> 3)) * 128 + (n & 7);
                for (int rg = 0; rg < 4; rg++)
                    ((unsigned short*)out)[base + (size_t)((srow0 & 15) + rg) * 8] = f2bf(acc[i][j][rg] + bj);
            } else if (MODE == 4) {
                size_t headb = ((size_t)bidx * HH + (n >> 6)) * (SS * HDD);
                size_t addr = headb + (size_t)(srow0 >> 6) * 4096 + (size_t)((n & 63) >> 4) * 1024 +
                              (size_t)(((srow0 >> 5) & 1) * 4 + ((srow0 >> 3) & 3)) * 128 +
                              (size_t)(n & 15) * 8 + (srow0 & 7);
                float v0 = acc[i][j][0] + bj, v1 = acc[i][j][1] + bj;
                float v2 = acc[i][j][2] + bj, v3 = acc[i][j][3] + bj;
                uint2 w;
                w.x = (unsigned int)f2bf(v0) | ((unsigned int)f2bf(v1) << 16);
                w.y = (unsigned int)f2bf(v2) | ((unsigned int)f2bf(v3) << 16);
                *(uint2*)&((unsigned short*)out)[addr] = w;
            } else {
                for (int rg = 0; rg < 4; rg++) {
                    float val = acc[i][j][rg] + bj;
                    int m = m0 + rg;
                    if (MODE == 0) {
                        ((unsigned short*)out)[(((size_t)(m >> 11) * HH + (n >> 6)) * SS + (m & 2047)) * HDD + (n & 63)] = f2bf(val);
                    } else {
                        ((float*)out)[(size_t)m * 1024 + n] = val;
                    }
                }
            }
        }
    }
}

// grid 768 1-D; XCD swizzle: same-by blocks share an XCD
__global__ __launch_bounds__(256) void gemm_qkv(
    const unsigned short* __restrict__ xb,
    const unsigned short* __restrict__ wqb, const unsigned short* __restrict__ wkb,
    const unsigned short* __restrict__ wvb,
    const float* __restrict__ bq, const float* __restrict__ bk, const float* __restrict__ bv,
    unsigned short* qb, unsigned short* kb, unsigned short* vtb) {
    __shared__ unsigned short shA[2 * 4096];   // shared across all 3 instantiations
    __shared__ unsigned short shB[2 * 4096];
    const int blk = blockIdx.x;
    const int u = blk & 7, r = blk >> 3;
    const int by = u + 8 * (r & 3);          // 0..31
    const int rest = r >> 2;                 // 0..23
    const int bx = rest & 7, z = rest >> 3;  // 0..7, 0..2
    if (z == 0)      gemm_core<0, 128, 128>(shA, shB, xb, wqb, bq, qb,  by * 128, bx * 128);
    else if (z == 1) gemm_core<3, 128, 128>(shA, shB, xb, wkb, bk, kb,  by * 128, bx * 128);
    else             gemm_core<4, 128, 128>(shA, shB, xb, wvb, bv, vtb, by * 128, bx * 128);
}

// grid 256 1-D (128x128 tiles)
__global__ __launch_bounds__(256) void gemm_out(
    const unsigned short* __restrict__ ob, const unsigned short* __restrict__ wob,
    const float* __restrict__ bo, float* __restrict__ out) {
    __shared__ unsigned short shA[2 * 4096];
    __shared__ unsigned short shB[2 * 4096];
    const int blk = blockIdx.x;
    const int u = blk & 7, r = blk >> 3;     // r: 0..31
    const int by = u + 8 * (r & 3);          // 0..31
    const int bx = r >> 2;                   // 0..7
    gemm_core<1, 128, 128>(shA, shB, ob, wob, bo, out, by * 128, bx * 128);
}

// ---------------- flash attention: INTRA-BLOCK SPLIT-K, 8 waves ----------------
// ROUND-16 state: 1-deep pipeline (PV(kt-1) register-only after barrier),
// setprio around pv(), K/V dbuf, 1 barrier/iter, in-register P transpose.
__global__ __launch_bounds__(512, 4) void attn_fwd(
    const unsigned short* __restrict__ qb, const unsigned short* __restrict__ kb,
    const unsigned short* __restrict__ vtb, unsigned short* __restrict__ ob) {
    __shared__ unsigned short sh[32768];  // lsK[2][2][4096] | lsV[2][2][4096]; combine aliases fit
    unsigned short* lsK = sh;
    unsigned short* lsV = sh + 16384;
    const int t = threadIdx.x, lane = t & 63, l15 = lane & 15, quad = lane >> 4;
    const int wave = t >> 6;          // 0..7
    const int half = wave >> 2;       // key-half
    const int wq = wave & 3;          // q-wave within half
    const int tg = t & 255;           // thread index within half-group
    const int blk = blockIdx.x;
    const int u = blk & 7, r = blk >> 3;
    const int bh = u + 8 * (r & 3);   // 0..31: 4 heads per XCD
    const int qt = r >> 2;            // 0..15
    const size_t hoff = (size_t)bh * (SS * HDD);
    const float C = 0.125f * 1.44269504088896f;  // 1/sqrt(HD) * log2(e)

    bf16x8 qf[2][2];
    const int qrow = qt * 128 + wq * 32;
    for (int i = 0; i < 2; i++)
        for (int ks = 0; ks < 2; ks++) {
            bf16x8 raw = *(const bf16x8*)&qb[hoff + (size_t)(qrow + i * 16 + l15) * HDD + ks * 32 + quad * 8];
            unsigned short tmp[8];
            *(bf16x8*)tmp = raw;
            for (int j = 0; j < 8; j++) {
                float f = __builtin_bit_cast(float, (unsigned int)tmp[j] << 16);
                tmp[j] = f2bf(f * C);
            }
            qf[i][ks] = *(const bf16x8*)tmp;
        }

    unsigned short onesbuf[8];
    for (int j = 0; j < 8; j++) onesbuf[j] = 0x3F80;  // bf16 1.0
    const bf16x8 onesf = *(const bf16x8*)onesbuf;

    f32x4 lacc[2];
    f32x4 o[2][4];
    for (int i = 0; i < 2; i++) {
        lacc[i] = (f32x4){0.f, 0.f, 0.f, 0.f};
        for (int jh = 0; jh < 4; jh++) o[i][jh] = (f32x4){0.f, 0.f, 0.f, 0.f};
    }

    const unsigned short* gk = kb + hoff + (size_t)half * 16 * 4096;
    const unsigned short* gv = vtb + hoff + (size_t)half * 16 * 4096;
    const int foff = quad * 128 + l15 * 8;

    auto stage = [&](int buf, int tile) {
        unsigned short* dk = lsK + buf * 8192 + half * 4096;
        unsigned short* dv = lsV + buf * 8192 + half * 4096;
        const unsigned short* sk = gk + tile * 4096;
        const unsigned short* sv = gv + tile * 4096;
        gll16(sk + tg * 8, dk + tg * 8);
        gll16(sk + 2048 + tg * 8, dk + 2048 + tg * 8);
        gll16(sv + tg * 8, dv + tg * 8);
        gll16(sv + 2048 + tg * 8, dv + 2048 + tg * 8);
    };

    bf16x8 pfp[2][2];
    bf16x8 vfp[4][2];

    auto qk_pack = [&](const unsigned short* myK) {
        bf16x8 kfr[4][2];
        for (int j = 0; j < 4; j++)
            for (int ks = 0; ks < 2; ks++)
                kfr[j][ks] = *(const bf16x8*)&myK[j * 1024 + ks * 512 + foff];
        f32x4 st[2][4];
        for (int j = 0; j < 4; j++)
            for (int i = 0; i < 2; i++) {
                f32x4 z = (f32x4){0.f, 0.f, 0.f, 0.f};
                z = MFMA16(kfr[j][0], qf[i][0], z);
                z = MFMA16(kfr[j][1], qf[i][1], z);
                st[i][j] = z;
            }
        for (int i = 0; i < 2; i++) {
            unsigned int W[4][2];
            for (int j = 0; j < 4; j++) {
                float e0 = __builtin_amdgcn_exp2f(st[i][j][0]);
                float e1 = __builtin_amdgcn_exp2f(st[i][j][1]);
                float e2 = __builtin_amdgcn_exp2f(st[i][j][2]);
                float e3 = __builtin_amdgcn_exp2f(st[i][j][3]);
                W[j][0] = (__builtin_bit_cast(unsigned int, e0) >> 16) |
                          (__builtin_bit_cast(unsigned int, e1) & 0xFFFF0000u);
                W[j][1] = (__builtin_bit_cast(unsigned int, e2) >> 16) |
                          (__builtin_bit_cast(unsigned int, e3) & 0xFFFF0000u);
            }
            unsigned int P0[4], P1[4];
            for (int h = 0; h < 2; h++) {
                unsigned int x = W[0][h], y = W[1][h];
                pl32swap(x, y);
                pl16swap(x, y);
                P0[h] = x; P0[2 + h] = y;
                unsigned int x2 = W[2][h], y2 = W[3][h];
                pl32swap(x2, y2);
                pl16swap(x2, y2);
                P1[h] = x2; P1[2 + h] = y2;
            }
            union { unsigned int u4[4]; bf16x8 v; } cv0, cv1;
            for (int p = 0; p < 4; p++) { cv0.u4[p] = P0[p]; cv1.u4[p] = P1[p]; }
            pfp[i][0] = cv0.v;
            pfp[i][1] = cv1.v;
        }
    };
    auto readV = [&](const unsigned short* myV) {
        for (int jh = 0; jh < 4; jh++) {
            vfp[jh][0] = *(const bf16x8*)&myV[jh * 1024 + foff];
            vfp[jh][1] = *(const bf16x8*)&myV[jh * 1024 + 512 + foff];
        }
    };
    auto pv = [&]() {
        __builtin_amdgcn_s_setprio(1);
        for (int jh = 0; jh < 4; jh++)
            for (int i = 0; i < 2; i++) {
                o[i][jh] = MFMA16(pfp[i][0], vfp[jh][0], o[i][jh]);
                o[i][jh] = MFMA16(pfp[i][1], vfp[jh][1], o[i][jh]);
            }
        for (int i = 0; i < 2; i++) {
            lacc[i] = MFMA16(pfp[i][0], onesf, lacc[i]);
            lacc[i] = MFMA16(pfp[i][1], onesf, lacc[i]);
        }
        __builtin_amdgcn_s_setprio(0);
    };

    stage(0, 0);

    __syncthreads();
    stage(1, 1);
    qk_pack(lsK + half * 4096);
    readV(lsV + half * 4096);

    for (int kt = 1; kt < 16; kt++) {
        const int cur = kt & 1;
        __syncthreads();
        if (kt < 15) stage(cur ^ 1, kt + 1);
        pv();
        const unsigned short* myK = lsK + cur * 8192 + half * 4096;
        const unsigned short* myV = lsV + cur * 8192 + half * 4096;
        qk_pack(myK);
        readV(myV);
    }
    pv();

    __syncthreads();
    float* cb = (float*)sh;
    float* lb = cb + 8192;
    const int lslot = wq * 64 + lane;
    if (half == 1) {
        for (int i = 0; i < 2; i++)
            for (int jh = 0; jh < 4; jh++)
                for (int rg = 0; rg < 4; rg++)
                    cb[(i * 16 + jh * 4 + rg) * 256 + lslot] = o[i][jh][rg];
        for (int i = 0; i < 2; i++)
            for (int rg = 0; rg < 4; rg++)
                lb[(i * 4 + rg) * 256 + lslot] = lacc[i][rg];
    }
    __syncthreads();
    if (half == 0) {
        const int b = bh >> 4, h = bh & 15;
        for (int i = 0; i < 2; i++)
            for (int rg = 0; rg < 4; rg++) {
                float inv = 1.f / (lacc[i][rg] + lb[(i * 4 + rg) * 256 + lslot]);
                int srow = qrow + i * 16 + quad * 4 + rg;
                size_t rowoff = ((size_t)b * SS + srow) * EE + h * 64;
                for (int jh = 0; jh < 4; jh++) {
                    float val = o[i][jh][rg] + cb[(i * 16 + jh * 4 + rg) * 256 + lslot];
                    ob[rowoff + jh * 16 + l15] = f2bf(val * inv);
                }
            }
    }
}

extern "C" void kernel_launch(void* const* d_in, const int* in_sizes, int n_in,
                              void* d_out, int out_size, void* d_ws, size_t ws_size,
                              hipStream_t stream) {
    const float* x  = (const float*)d_in[0];
    const float* wq = (const float*)d_in[1];
    const float* bq = (const float*)d_in[2];
    const float* wk = (const float*)d_in[3];
    const float* bk = (const float*)d_in[4];
    const float* wv = (const float*)d_in[5];
    const float* bv = (const float*)d_in[6];
    const float* wo = (const float*)d_in[7];
    const float* bo = (const float*)d_in[8];

    char* ws = (char*)d_ws;
    unsigned short* xb  = (unsigned short*)(ws + 0);          // 8 MB, reused as ob after qkv
    unsigned short* wqb = (unsigned short*)(ws + 8388608);    // 2 MB
    unsigned short* wkb = (unsigned short*)(ws + 10485760);
    unsigned short* wvb = (unsigned short*)(ws + 12582912);
    unsigned short* wob = (unsigned short*)(ws + 14680064);
    unsigned short* qb  = (unsigned short*)(ws + 16777216);   // 8 MB each
    unsigned short* kb  = (unsigned short*)(ws + 25165824);   // K in fragment order
    unsigned short* vtb = (unsigned short*)(ws + 33554432);   // V in fragment order
    unsigned short* ob  = xb;  // x no longer needed after qkv GEMM

    cvt_all<<<8192, 256, 0, stream>>>(x, wq, wk, wv, wo, xb, wqb, wkb, wvb, wob);
    gemm_qkv<<<768, 256, 0, stream>>>(xb, wqb, wkb, wvb, bq, bk, bv, qb, kb, vtb);
    attn_fwd<<<512, 512, 0, stream>>>(qb, kb, vtb, ob);
    gemm_out<<<256, 256, 0, stream>>>(ob, wob, bo, (float*)d_out);
}

// Round 11
// 186.790 us; speedup vs baseline: 1.1415x; 1.0404x over previous
//
#include <hip/hip_runtime.h>
#include <hip/hip_bf16.h>
#include <cstdint>

// B=2, S=2048, E=1024, H=16, HD=64
#define SS 2048
#define EE 1024
#define HH 16
#define HDD 64

typedef __attribute__((ext_vector_type(8))) __bf16 bf16x8;
typedef __attribute__((ext_vector_type(4))) float f32x4;

#define MFMA16(a, b, c) __builtin_amdgcn_mfma_f32_16x16x32_bf16((a), (b), (c), 0, 0, 0)

__device__ __forceinline__ unsigned short f2bf(float f) {
    unsigned int u = __builtin_bit_cast(unsigned int, f);
    u += 0x7FFFu + ((u >> 16) & 1u);   // round-to-nearest-even
    return (unsigned short)(u >> 16);
}

// async global->LDS, 16B per lane; LDS dest is wave-uniform base + lane*16
__device__ __forceinline__ void gll16(const unsigned short* g, unsigned short* l) {
    __builtin_amdgcn_global_load_lds(
        (__attribute__((address_space(1))) unsigned int*)g,
        (__attribute__((address_space(3))) unsigned int*)l, 16, 0, 0);
}

// v_permlane32_swap_b32: a' = {A.low32, B.low32}, b' = {A.high32, B.high32}
__device__ __forceinline__ void pl32swap(unsigned int& a, unsigned int& b) {
#if __has_builtin(__builtin_amdgcn_permlane32_swap)
    auto r = __builtin_amdgcn_permlane32_swap(a, b, false, false);
    a = r[0]; b = r[1];
#else
    unsigned int as = __shfl_xor(a, 32, 64), bs = __shfl_xor(b, 32, 64);
    const bool hi = (threadIdx.x & 32) != 0;
    unsigned int na = hi ? bs : a, nb = hi ? b : as;
    a = na; b = nb;
#endif
}

// v_permlane16_swap_b32: a' = {A.r0, B.r0, A.r2, B.r2}, b' = {A.r1, B.r1, A.r3, B.r3}  (16-lane rows)
__device__ __forceinline__ void pl16swap(unsigned int& a, unsigned int& b) {
#if __has_builtin(__builtin_amdgcn_permlane16_swap)
    auto r = __builtin_amdgcn_permlane16_swap(a, b, false, false);
    a = r[0]; b = r[1];
#else
    unsigned int as = __shfl_xor(a, 16, 64), bs = __shfl_xor(b, 16, 64);
    const bool odd = (threadIdx.x & 16) != 0;
    unsigned int na = odd ? bs : a, nb = odd ? b : as;
    a = na; b = nb;
#endif
}

// ---------------- fp32 -> bf16 convert (x + 4 weights) ----------------
__global__ __launch_bounds__(256) void cvt_all(
    const float* __restrict__ x, const float* __restrict__ wq, const float* __restrict__ wk,
    const float* __restrict__ wv, const float* __restrict__ wo,
    unsigned short* __restrict__ xb, unsigned short* __restrict__ wqb, unsigned short* __restrict__ wkb,
    unsigned short* __restrict__ wvb, unsigned short* __restrict__ wob) {
    int idx = blockIdx.x * 256 + threadIdx.x;
    int i4 = idx << 2;                       // 4 floats per thread
    const float* src;
    unsigned short* dst;
    int off;
    if (i4 < 4194304) { src = x; dst = xb; off = i4; }
    else {
        int w = (i4 - 4194304) >> 20;        // 0..3
        off = (i4 - 4194304) & 1048575;
        if (w == 0) { src = wq; dst = wqb; }
        else if (w == 1) { src = wk; dst = wkb; }
        else if (w == 2) { src = wv; dst = wvb; }
        else { src = wo; dst = wob; }
    }
    float4 v = *(const float4*)&src[off];
    unsigned int p0 = (unsigned int)f2bf(v.x) | ((unsigned int)f2bf(v.y) << 16);
    unsigned int p1 = (unsigned int)f2bf(v.z) | ((unsigned int)f2bf(v.w) << 16);
    uint2 u; u.x = p0; u.y = p1;
    *(uint2*)&dst[off] = u;
}

// ---------------- BT GEMM, DOUBLE-BUFFERED (one barrier per K-iter) ----------------
// FINAL CONFIG. Both operands LDS-staged (B reg-stream shifted traffic to L2 and
// exceeded its ceiling: round-9, 65us; staging deduplicates B across the 4 waves).
// 128x128 qkv tiles (256^2 asm-pipeline port spilled acc: round-7). gemm_out at
// 128x64 grid 512: 2 blocks/CU beats 128x128's 1 block/CU (no cross-block TLP) --
// the two best session totals (187.8/188.4) both ran this config.
// MODE 0: bf16 Q [B,H,S,HD]; MODE 1: fp32 [M,N];
// MODE 3: K in MFMA A-frag order; MODE 4: V in MFMA B-frag order.
template <int MODE, int BMT, int BNT>
__device__ __forceinline__ void gemm_core(
    unsigned short* __restrict__ lsA,        // [2][BMT*32]
    unsigned short* __restrict__ lsB,        // [2][BNT*32]
    const unsigned short* __restrict__ A, const unsigned short* __restrict__ W,
    const float* __restrict__ bias, void* __restrict__ out, int bm, int bn) {
    constexpr int IT = BMT / 32, JT = BNT / 32;
    constexpr int ASTR = BMT * 32, BSTR = BNT * 32;
    const int t = threadIdx.x;
    const int lane = t & 63, l15 = lane & 15, quad = lane >> 4;
    const int wave = t >> 6;
    const int wm = (wave >> 1) * (BMT / 2), wn = (wave & 1) * (BNT / 2);

    // staging: lane t -> physical chunk (t&3) of row (t>>2); load logical chunk (t&3)^((t>>3)&3)
    const int cg = ((t & 3) ^ ((t >> 3) & 3)) * 8;
    const unsigned short* ga = A + (size_t)(bm + (t >> 2)) * 1024 + cg;
    const unsigned short* gb = W + (size_t)(bn + (t >> 2)) * 1024 + cg;

    f32x4 acc[IT][JT];
    for (int i = 0; i < IT; i++)
        for (int j = 0; j < JT; j++) acc[i][j] = (f32x4){0.f, 0.f, 0.f, 0.f};

    const int swz = (l15 >> 1) & 3;  // (row>>1)&3 for row = wX + i*16 + l15

    // stage K-slab 0 into buffer 0
    gll16(ga, &lsA[t * 8]);
    if (BMT == 128) gll16(ga + 64 * 1024, &lsA[2048 + t * 8]);
    gll16(gb, &lsB[t * 8]);
    if (BNT == 128) gll16(gb + 64 * 1024, &lsB[2048 + t * 8]);

    for (int it = 0; it < 32; it++) {
        const int cur = it & 1, nxt = cur ^ 1;
        __syncthreads();  // cur staging done (issued a full body ago); prev reads of nxt drained

        if (it < 31) {
            const int k0 = (it + 1) * 32;
            gll16(ga + k0, &lsA[nxt * ASTR + t * 8]);
            if (BMT == 128) gll16(ga + k0 + 64 * 1024, &lsA[nxt * ASTR + 2048 + t * 8]);
            gll16(gb + k0, &lsB[nxt * BSTR + t * 8]);
            if (BNT == 128) gll16(gb + k0 + 64 * 1024, &lsB[nxt * BSTR + 2048 + t * 8]);
        }

        bf16x8 af[IT], bfr[JT];
        for (int i = 0; i < IT; i++)
            af[i] = *(const bf16x8*)&lsA[cur * ASTR + (wm + i * 16 + l15) * 32 + ((quad ^ swz) * 8)];
        for (int j = 0; j < JT; j++)
            bfr[j] = *(const bf16x8*)&lsB[cur * BSTR + (wn + j * 16 + l15) * 32 + ((quad ^ swz) * 8)];
        for (int i = 0; i < IT; i++)
            for (int j = 0; j < JT; j++) acc[i][j] = MFMA16(af[i], bfr[j], acc[i][j]);
    }

    // epilogue: C row = quad*4+reg, col = l15 per 16x16 tile (m89-verified)
    for (int j = 0; j < JT; j++) {
        int n = bn + wn + j * 16 + l15;
        float bj = bias[n];
        for (int i = 0; i < IT; i++) {
            int m0 = bm + wm + i * 16 + quad * 4;
            int srow0 = m0 & 2047, bidx = m0 >> 11;
            if (MODE == 3) {
                size_t headb = ((size_t)bidx * HH + (n >> 6)) * (SS * HDD);
                size_t base = headb + (size_t)(srow0 >> 6) * 4096 +
                              (size_t)(((srow0 >> 4) & 3) * 8 + ((n & 63) >> 3)) * 128 + (n & 7);
                for (int rg = 0; rg < 4; rg++)
                    ((unsigned short*)out)[base + (size_t)((srow0 & 15) + rg) * 8] = f2bf(acc[i][j][rg] + bj);
            } else if (MODE == 4) {
                size_t headb = ((size_t)bidx * HH + (n >> 6)) * (SS * HDD);
                size_t addr = headb + (size_t)(srow0 >> 6) * 4096 + (size_t)((n & 63) >> 4) * 1024 +
                              (size_t)(((srow0 >> 5) & 1) * 4 + ((srow0 >> 3) & 3)) * 128 +
                              (size_t)(n & 15) * 8 + (srow0 & 7);
                float v0 = acc[i][j][0] + bj, v1 = acc[i][j][1] + bj;
                float v2 = acc[i][j][2] + bj, v3 = acc[i][j][3] + bj;
                uint2 w;
                w.x = (unsigned int)f2bf(v0) | ((unsigned int)f2bf(v1) << 16);
                w.y = (unsigned int)f2bf(v2) | ((unsigned int)f2bf(v3) << 16);
                *(uint2*)&((unsigned short*)out)[addr] = w;
            } else {
                for (int rg = 0; rg < 4; rg++) {
                    float val = acc[i][j][rg] + bj;
                    int m = m0 + rg;
                    if (MODE == 0) {
                        ((unsigned short*)out)[(((size_t)(m >> 11) * HH + (n >> 6)) * SS + (m & 2047)) * HDD + (n & 63)] = f2bf(val);
                    } else {
                        ((float*)out)[(size_t)m * 1024 + n] = val;
                    }
                }
            }
        }
    }
}

// grid 768 1-D; XCD swizzle: same-by blocks share an XCD
__global__ __launch_bounds__(256) void gemm_qkv(
    const unsigned short* __restrict__ xb,
    const unsigned short* __restrict__ wqb, const unsigned short* __restrict__ wkb,
    const unsigned short* __restrict__ wvb,
    const float* __restrict__ bq, const float* __restrict__ bk, const float* __restrict__ bv,
    unsigned short* qb, unsigned short* kb, unsigned short* vtb) {
    __shared__ unsigned short shA[2 * 4096];   // shared across all 3 instantiations
    __shared__ unsigned short shB[2 * 4096];
    const int blk = blockIdx.x;
    const int u = blk & 7, r = blk >> 3;
    const int by = u + 8 * (r & 3);          // 0..31
    const int rest = r >> 2;                 // 0..23
    const int bx = rest & 7, z = rest >> 3;  // 0..7, 0..2
    if (z == 0)      gemm_core<0, 128, 128>(shA, shB, xb, wqb, bq, qb,  by * 128, bx * 128);
    else if (z == 1) gemm_core<3, 128, 128>(shA, shB, xb, wkb, bk, kb,  by * 128, bx * 128);
    else             gemm_core<4, 128, 128>(shA, shB, xb, wvb, bv, vtb, by * 128, bx * 128);
}

// grid 512 1-D (128x64 tiles, 2 blocks/CU -- best-measured config)
__global__ __launch_bounds__(256) void gemm_out(
    const unsigned short* __restrict__ ob, const unsigned short* __restrict__ wob,
    const float* __restrict__ bo, float* __restrict__ out) {
    __shared__ unsigned short shA[2 * 4096];
    __shared__ unsigned short shB[2 * 2048];
    const int blk = blockIdx.x;
    const int u = blk & 7, r = blk >> 3;
    const int by = u + 8 * (r & 3);          // 0..31
    const int bx = r >> 2;                   // 0..15
    gemm_core<1, 128, 64>(shA, shB, ob, wob, bo, out, by * 128, bx * 64);
}

// ---------------- flash attention: INTRA-BLOCK SPLIT-K, 8 waves ----------------
// FINAL: 1-deep pipeline (PV(kt-1) register-only after barrier), setprio around
// pv(), K/V dbuf, 1 barrier/iter, in-register P transpose (permlane32/16),
// ones-MFMA denominator. 2 blocks/CU.
__global__ __launch_bounds__(512, 4) void attn_fwd(
    const unsigned short* __restrict__ qb, const unsigned short* __restrict__ kb,
    const unsigned short* __restrict__ vtb, unsigned short* __restrict__ ob) {
    __shared__ unsigned short sh[32768];  // lsK[2][2][4096] | lsV[2][2][4096]; combine aliases fit
    unsigned short* lsK = sh;
    unsigned short* lsV = sh + 16384;
    const int t = threadIdx.x, lane = t & 63, l15 = lane & 15, quad = lane >> 4;
    const int wave = t >> 6;          // 0..7
    const int half = wave >> 2;       // key-half
    const int wq = wave & 3;          // q-wave within half
    const int tg = t & 255;           // thread index within half-group
    const int blk = blockIdx.x;
    const int u = blk & 7, r = blk >> 3;
    const int bh = u + 8 * (r & 3);   // 0..31: 4 heads per XCD
    const int qt = r >> 2;            // 0..15
    const size_t hoff = (size_t)bh * (SS * HDD);
    const float C = 0.125f * 1.44269504088896f;  // 1/sqrt(HD) * log2(e)

    bf16x8 qf[2][2];
    const int qrow = qt * 128 + wq * 32;
    for (int i = 0; i < 2; i++)
        for (int ks = 0; ks < 2; ks++) {
            bf16x8 raw = *(const bf16x8*)&qb[hoff + (size_t)(qrow + i * 16 + l15) * HDD + ks * 32 + quad * 8];
            unsigned short tmp[8];
            *(bf16x8*)tmp = raw;
            for (int j = 0; j < 8; j++) {
                float f = __builtin_bit_cast(float, (unsigned int)tmp[j] << 16);
                tmp[j] = f2bf(f * C);
            }
            qf[i][ks] = *(const bf16x8*)tmp;
        }

    unsigned short onesbuf[8];
    for (int j = 0; j < 8; j++) onesbuf[j] = 0x3F80;  // bf16 1.0
    const bf16x8 onesf = *(const bf16x8*)onesbuf;

    f32x4 lacc[2];
    f32x4 o[2][4];
    for (int i = 0; i < 2; i++) {
        lacc[i] = (f32x4){0.f, 0.f, 0.f, 0.f};
        for (int jh = 0; jh < 4; jh++) o[i][jh] = (f32x4){0.f, 0.f, 0.f, 0.f};
    }

    const unsigned short* gk = kb + hoff + (size_t)half * 16 * 4096;
    const unsigned short* gv = vtb + hoff + (size_t)half * 16 * 4096;
    const int foff = quad * 128 + l15 * 8;

    auto stage = [&](int buf, int tile) {
        unsigned short* dk = lsK + buf * 8192 + half * 4096;
        unsigned short* dv = lsV + buf * 8192 + half * 4096;
        const unsigned short* sk = gk + tile * 4096;
        const unsigned short* sv = gv + tile * 4096;
        gll16(sk + tg * 8, dk + tg * 8);
        gll16(sk + 2048 + tg * 8, dk + 2048 + tg * 8);
        gll16(sv + tg * 8, dv + tg * 8);
        gll16(sv + 2048 + tg * 8, dv + 2048 + tg * 8);
    };

    bf16x8 pfp[2][2];
    bf16x8 vfp[4][2];

    auto qk_pack = [&](const unsigned short* myK) {
        bf16x8 kfr[4][2];
        for (int j = 0; j < 4; j++)
            for (int ks = 0; ks < 2; ks++)
                kfr[j][ks] = *(const bf16x8*)&myK[j * 1024 + ks * 512 + foff];
        f32x4 st[2][4];
        for (int j = 0; j < 4; j++)
            for (int i = 0; i < 2; i++) {
                f32x4 z = (f32x4){0.f, 0.f, 0.f, 0.f};
                z = MFMA16(kfr[j][0], qf[i][0], z);
                z = MFMA16(kfr[j][1], qf[i][1], z);
                st[i][j] = z;
            }
        for (int i = 0; i < 2; i++) {
            unsigned int W[4][2];
            for (int j = 0; j < 4; j++) {
                float e0 = __builtin_amdgcn_exp2f(st[i][j][0]);
                float e1 = __builtin_amdgcn_exp2f(st[i][j][1]);
                float e2 = __builtin_amdgcn_exp2f(st[i][j][2]);
                float e3 = __builtin_amdgcn_exp2f(st[i][j][3]);
                W[j][0] = (__builtin_bit_cast(unsigned int, e0) >> 16) |
                          (__builtin_bit_cast(unsigned int, e1) & 0xFFFF0000u);
                W[j][1] = (__builtin_bit_cast(unsigned int, e2) >> 16) |
                          (__builtin_bit_cast(unsigned int, e3) & 0xFFFF0000u);
            }
            unsigned int P0[4], P1[4];
            for (int h = 0; h < 2; h++) {
                unsigned int x = W[0][h], y = W[1][h];
                pl32swap(x, y);
                pl16swap(x, y);
                P0[h] = x; P0[2 + h] = y;
                unsigned int x2 = W[2][h], y2 = W[3][h];
                pl32swap(x2, y2);
                pl16swap(x2, y2);
                P1[h] = x2; P1[2 + h] = y2;
            }
            union { unsigned int u4[4]; bf16x8 v; } cv0, cv1;
            for (int p = 0; p < 4; p++) { cv0.u4[p] = P0[p]; cv1.u4[p] = P1[p]; }
            pfp[i][0] = cv0.v;
            pfp[i][1] = cv1.v;
        }
    };
    auto readV = [&](const unsigned short* myV) {
        for (int jh = 0; jh < 4; jh++) {
            vfp[jh][0] = *(const bf16x8*)&myV[jh * 1024 + foff];
            vfp[jh][1] = *(const bf16x8*)&myV[jh * 1024 + 512 + foff];
        }
    };
    auto pv = [&]() {
        __builtin_amdgcn_s_setprio(1);
        for (int jh = 0; jh < 4; jh++)
            for (int i = 0; i < 2; i++) {
                o[i][jh] = MFMA16(pfp[i][0], vfp[jh][0], o[i][jh]);
                o[i][jh] = MFMA16(pfp[i][1], vfp[jh][1], o[i][jh]);
            }
        for (int i = 0; i < 2; i++) {
            lacc[i] = MFMA16(pfp[i][0], onesf, lacc[i]);
            lacc[i] = MFMA16(pfp[i][1], onesf, lacc[i]);
        }
        __builtin_amdgcn_s_setprio(0);
    };

    stage(0, 0);

    __syncthreads();
    stage(1, 1);
    qk_pack(lsK + half * 4096);
    readV(lsV + half * 4096);

    for (int kt = 1; kt < 16; kt++) {
        const int cur = kt & 1;
        __syncthreads();
        if (kt < 15) stage(cur ^ 1, kt + 1);
        pv();
        const unsigned short* myK = lsK + cur * 8192 + half * 4096;
        const unsigned short* myV = lsV + cur * 8192 + half * 4096;
        qk_pack(myK);
        readV(myV);
    }
    pv();

    __syncthreads();
    float* cb = (float*)sh;
    float* lb = cb + 8192;
    const int lslot = wq * 64 + lane;
    if (half == 1) {
        for (int i = 0; i < 2; i++)
            for (int jh = 0; jh < 4; jh++)
                for (int rg = 0; rg < 4; rg++)
                    cb[(i * 16 + jh * 4 + rg) * 256 + lslot] = o[i][jh][rg];
        for (int i = 0; i < 2; i++)
            for (int rg = 0; rg < 4; rg++)
                lb[(i * 4 + rg) * 256 + lslot] = lacc[i][rg];
    }
    __syncthreads();
    if (half == 0) {
        const int b = bh >> 4, h = bh & 15;
        for (int i = 0; i < 2; i++)
            for (int rg = 0; rg < 4; rg++) {
                float inv = 1.f / (lacc[i][rg] + lb[(i * 4 + rg) * 256 + lslot]);
                int srow = qrow + i * 16 + quad * 4 + rg;
                size_t rowoff = ((size_t)b * SS + srow) * EE + h * 64;
                for (int jh = 0; jh < 4; jh++) {
                    float val = o[i][jh][rg] + cb[(i * 16 + jh * 4 + rg) * 256 + lslot];
                    ob[rowoff + jh * 16 + l15] = f2bf(val * inv);
                }
            }
    }
}

extern "C" void kernel_launch(void* const* d_in, const int* in_sizes, int n_in,
                              void* d_out, int out_size, void* d_ws, size_t ws_size,
                              hipStream_t stream) {
    const float* x  = (const float*)d_in[0];
    const float* wq = (const float*)d_in[1];
    const float* bq = (const float*)d_in[2];
    const float* wk = (const float*)d_in[3];
    const float* bk = (const float*)d_in[4];
    const float* wv = (const float*)d_in[5];
    const float* bv = (const float*)d_in[6];
    const float* wo = (const float*)d_in[7];
    const float* bo = (const float*)d_in[8];

    char* ws = (char*)d_ws;
    unsigned short* xb  = (unsigned short*)(ws + 0);          // 8 MB, reused as ob after qkv
    unsigned short* wqb = (unsigned short*)(ws + 8388608);    // 2 MB
    unsigned short* wkb = (unsigned short*)(ws + 10485760);
    unsigned short* wvb = (unsigned short*)(ws + 12582912);
    unsigned short* wob = (unsigned short*)(ws + 14680064);
    unsigned short* qb  = (unsigned short*)(ws + 16777216);   // 8 MB each
    unsigned short* kb  = (unsigned short*)(ws + 25165824);   // K in fragment order
    unsigned short* vtb = (unsigned short*)(ws + 33554432);   // V in fragment order
    unsigned short* ob  = xb;  // x no longer needed after qkv GEMM

    cvt_all<<<8192, 256, 0, stream>>>(x, wq, wk, wv, wo, xb, wqb, wkb, wvb, wob);
    gemm_qkv<<<768, 256, 0, stream>>>(xb, wqb, wkb, wvb, bq, bk, bv, qb, kb, vtb);
    attn_fwd<<<512, 512, 0, stream>>>(qb, kb, vtb, ob);
    gemm_out<<<512, 256, 0, stream>>>(ob, wob, bo, (float*)d_out);
}